// Round 19
// baseline (151.781 us; speedup 1.0000x reference)
//
#include <hip/hip_runtime.h>
#include <stdint.h>

typedef uint32_t u32;
typedef __attribute__((ext_vector_type(4))) float f32x4;
typedef __attribute__((ext_vector_type(8))) short short8;

#define NBATCH 16
#define NPIX   16384      // H*W
#define NPB    1048576    // per-batch flat elems (C*H*W = 1024*1024)

__device__ __forceinline__ ushort f2bf(float f) {
  u32 b = __builtin_bit_cast(u32, f);
  return (ushort)((b + 0x7FFFu + ((b >> 16) & 1u)) >> 16);
}
__device__ __forceinline__ float bf2f(ushort h) {
  return __builtin_bit_cast(float, (u32)h << 16);
}

// async global->LDS, 16B per lane. LDS dest must be wave-uniform base;
// HW scatters lane i at base + i*16. Global source is per-lane.
__device__ __forceinline__ void gload16(const void* g, void* l) {
  __builtin_amdgcn_global_load_lds(
      (const __attribute__((address_space(1))) u32*)g,
      (__attribute__((address_space(3))) u32*)l,
      16, 0, 0);
}

// ---------------- Kernel 0: pack weights for MFMA-proj -----------------------
__global__ void prep_w2(const float* __restrict__ Wq, const float* __restrict__ bq,
                        const float* __restrict__ Wk, const float* __restrict__ bk,
                        const float* __restrict__ Wv, const float* __restrict__ bv,
                        ushort* __restrict__ Wpk, float* __restrict__ bpk)
{
  int gid = blockIdx.x * 256 + threadIdx.x;
  if (gid < 12288) {
    int m = gid >> 7, kk = gid & 127;
    int ch = kk & 63;
    ushort outv = 0;
    if (m < 8) {
      float wv = Wq[m * 64 + ch];
      ushort h = f2bf(wv);
      outv = (kk < 64) ? h : f2bf(wv - bf2f(h));
    } else if (m < 16) {
      float wv = Wk[(m - 8) * 64 + ch];
      ushort h = f2bf(wv);
      outv = (kk < 64) ? h : f2bf(wv - bf2f(h));
    } else if (m < 80) {
      outv = (kk < 64) ? f2bf(Wv[(m - 16) * 64 + ch]) : (ushort)0;
    }
    Wpk[gid] = outv;
  } else if (gid < 12368) {
    int o = gid - 12288;
    bpk[o] = (o < 8) ? bq[o] : (o < 16 ? bk[o - 8] : bv[o - 16]);
  }
}

// ---------------- Kernel 1: MFMA proj + fused transposes (R15-verified) ------
__global__ __launch_bounds__(256) void proj10(
    const float* __restrict__ x, const ushort* __restrict__ Wpk,
    const float* __restrict__ bpk,
    ushort* __restrict__ Qt2, ushort* __restrict__ Kt2,
    ushort* __restrict__ Vt)
{
  __shared__ __align__(16) char smem[32768];
  float* xs = (float*)smem;                       // [64][128]
  int t = threadIdx.x;
  int w = t >> 6, lane = t & 63;
  int l15 = lane & 15, l4 = lane >> 4;

  int g = blockIdx.x;
  int lin = (g & 7) * 256 + (g >> 3);
  int b = lin >> 7;
  int l0 = (lin & 127) << 3;
  const float* xb = x + (size_t)b * NPB + l0;

  #pragma unroll
  for (int it = 0; it < 8; ++it) {
    int f0 = (it * 4 + w) * 64;
    int f = f0 + lane;
    int ch = f >> 5, r2 = f & 31, tc = r2 >> 1, half = r2 & 1;
    gload16(xb + (size_t)ch * NPIX + tc * 1024 + half * 4, xs + f0 * 4);
  }

  const uint4* Wp4 = (const uint4*)Wpk;   // row stride 16 uint4
  uint4 Afrag[12];
  #pragma unroll
  for (int kc = 0; kc < 4; ++kc)
    Afrag[kc] = Wp4[l15 * 16 + kc * 4 + l4];
  #pragma unroll
  for (int mt = 1; mt < 5; ++mt)
    #pragma unroll
    for (int kc = 0; kc < 2; ++kc)
      Afrag[2 + mt * 2 + kc] = Wp4[(mt * 16 + l15) * 16 + kc * 4 + l4];

  f32x4 acc[5][2];
  #pragma unroll
  for (int mt = 0; mt < 5; ++mt) {
    f32x4 bv4;
    #pragma unroll
    for (int r = 0; r < 4; ++r) bv4[r] = bpk[mt * 16 + l4 * 4 + r];
    acc[mt][0] = bv4; acc[mt][1] = bv4;
  }

  __syncthreads();

  #pragma unroll
  for (int i = 0; i < 2; ++i) {
    int px = (w * 2 + i) * 16 + l15;
    u32 xr[16];
    #pragma unroll
    for (int kc = 0; kc < 2; ++kc)
      #pragma unroll
      for (int j = 0; j < 8; ++j)
        xr[kc * 8 + j] = ((const u32*)xs)[(kc * 32 + l4 * 8 + j) * 128 + px];
    uint4 bxh[2], bxl[2];
    #pragma unroll
    for (int kc = 0; kc < 2; ++kc)
      #pragma unroll
      for (int p = 0; p < 4; ++p) {
        u32 a = xr[kc * 8 + 2 * p], c = xr[kc * 8 + 2 * p + 1];
        ((u32*)&bxh[kc])[p] = (a >> 16) | (c & 0xFFFF0000u);
        float fa = __builtin_bit_cast(float, a) -
                   __builtin_bit_cast(float, a & 0xFFFF0000u);
        float fc = __builtin_bit_cast(float, c) -
                   __builtin_bit_cast(float, c & 0xFFFF0000u);
        u32 la = __builtin_bit_cast(u32, fa), lc = __builtin_bit_cast(u32, fc);
        ((u32*)&bxl[kc])[p] = (la >> 16) | (lc & 0xFFFF0000u);
      }
    short8 h0 = __builtin_bit_cast(short8, bxh[0]);
    short8 h1 = __builtin_bit_cast(short8, bxh[1]);
    short8 s0 = __builtin_bit_cast(short8, bxl[0]);
    short8 s1 = __builtin_bit_cast(short8, bxl[1]);
    acc[0][i] = __builtin_amdgcn_mfma_f32_16x16x32_bf16(
        __builtin_bit_cast(short8, Afrag[0]), h0, acc[0][i], 0, 0, 0);
    acc[0][i] = __builtin_amdgcn_mfma_f32_16x16x32_bf16(
        __builtin_bit_cast(short8, Afrag[1]), h1, acc[0][i], 0, 0, 0);
    acc[0][i] = __builtin_amdgcn_mfma_f32_16x16x32_bf16(
        __builtin_bit_cast(short8, Afrag[0]), s0, acc[0][i], 0, 0, 0);
    acc[0][i] = __builtin_amdgcn_mfma_f32_16x16x32_bf16(
        __builtin_bit_cast(short8, Afrag[1]), s1, acc[0][i], 0, 0, 0);
    acc[0][i] = __builtin_amdgcn_mfma_f32_16x16x32_bf16(
        __builtin_bit_cast(short8, Afrag[2]), h0, acc[0][i], 0, 0, 0);
    acc[0][i] = __builtin_amdgcn_mfma_f32_16x16x32_bf16(
        __builtin_bit_cast(short8, Afrag[3]), h1, acc[0][i], 0, 0, 0);
    #pragma unroll
    for (int mt = 1; mt < 5; ++mt) {
      acc[mt][i] = __builtin_amdgcn_mfma_f32_16x16x32_bf16(
          __builtin_bit_cast(short8, Afrag[2 + mt * 2]), h0, acc[mt][i], 0, 0, 0);
      acc[mt][i] = __builtin_amdgcn_mfma_f32_16x16x32_bf16(
          __builtin_bit_cast(short8, Afrag[3 + mt * 2]), h1, acc[mt][i], 0, 0, 0);
    }
  }
  __syncthreads();

  float*  qkl = (float*)smem;                    // [16][132]
  ushort* vl  = (ushort*)(smem + 16 * 132 * 4);  // [64][136]
  #pragma unroll
  for (int i = 0; i < 2; ++i) {
    int px = (w * 2 + i) * 16 + l15;
    #pragma unroll
    for (int r = 0; r < 4; ++r)
      qkl[(l4 * 4 + r) * 132 + px] = acc[0][i][r];
    #pragma unroll
    for (int mt = 1; mt < 5; ++mt)
      #pragma unroll
      for (int r = 0; r < 4; ++r)
        vl[((mt - 1) * 16 + l4 * 4 + r) * 136 + px] = f2bf(acc[mt][i][r]);
  }
  __syncthreads();

  if (t < 128) {
    int l = t >> 4, tcc = t & 15;
    size_t lrow = (size_t)b * 1024 + l0 + l;
    int px = tcc * 8 + l;

    union { ushort s[8]; uint4 v; } qh, ql, kh, kl;
    #pragma unroll
    for (int o = 0; o < 8; ++o) {
      float qv = qkl[o * 132 + px];
      ushort h = f2bf(qv);
      qh.s[o] = h; ql.s[o] = f2bf(qv - bf2f(h));
      float kv = qkl[(8 + o) * 132 + px];
      h = f2bf(kv);
      kh.s[o] = h; kl.s[o] = f2bf(kv - bf2f(h));
    }
    ushort* qrow = Qt2 + lrow * 384 + tcc * 8;
    *(uint4*)qrow         = qh.v;
    *(uint4*)(qrow + 128) = ql.v;
    *(uint4*)(qrow + 256) = qh.v;
    ushort* krow = Kt2 + lrow * 384 + tcc * 8;
    *(uint4*)krow         = kh.v;
    *(uint4*)(krow + 128) = kh.v;
    *(uint4*)(krow + 256) = kl.v;

    ushort* vrow = Vt + lrow * 1024;
    #pragma unroll
    for (int it = 0; it < 4; ++it) {
      int c2 = (it << 4) + tcc;
      union { ushort s[16]; uint4 q[2]; } ov;
      #pragma unroll
      for (int tt = 0; tt < 16; ++tt)
        ov.s[tt] = vl[c2 * 136 + tt * 8 + l];
      *(uint4*)(vrow + c2 * 16)     = ov.q[0];
      *(uint4*)(vrow + c2 * 16 + 8) = ov.q[1];
    }
  }
}

// ---------------- Kernel 2: 256x256 NT bf16 GEMM (R17-verified, gemm1) -------
template<int KTOT, bool ADDX>
__global__ __launch_bounds__(512, 2) void gemm256(
    const ushort* __restrict__ A, int lda,
    const ushort* __restrict__ B, int ldb,
    float* __restrict__ C, const float* __restrict__ X)
{
  __shared__ ushort AB[2][2][16384];   // [buf][A/B][256*64]
  int t = threadIdx.x;

  int g = blockIdx.x;
  int lin = (g & 7) * 32 + (g >> 3);
  int bz = lin >> 4;
  int by = (lin >> 2) & 3;
  int bx = lin & 3;
  int m0 = by << 8, n0 = bx << 8;

  const ushort* Ab = A + (size_t)bz * 1024 * lda;
  const ushort* Bb = B + (size_t)bz * 1024 * ldb;
  int w = t >> 6, lane = t & 63;
  int wm = w >> 2, wn = w & 3;
  int l15 = lane & 15, l4 = lane >> 4;

  int swc = (t & 7) ^ ((t >> 3) & 7);
  const ushort* pa = Ab + (size_t)(m0 + (t >> 3)) * lda + swc * 8;
  const ushort* pb = Bb + (size_t)(n0 + (t >> 3)) * ldb + swc * 8;
  int wb = w * 512;

  f32x4 acc[8][4] = {};
  constexpr int NT = KTOT / 64;

  #pragma unroll
  for (int i = 0; i < 4; ++i)
    gload16(pa + (size_t)i * 64 * lda, AB[0][0] + i * 4096 + wb);
  #pragma unroll
  for (int i = 0; i < 4; ++i)
    gload16(pb + (size_t)i * 64 * ldb, AB[0][1] + i * 4096 + wb);
  #pragma unroll
  for (int i = 0; i < 4; ++i)
    gload16(pa + (size_t)i * 64 * lda + 64, AB[1][0] + i * 4096 + wb);
  #pragma unroll
  for (int i = 0; i < 4; ++i)
    gload16(pb + (size_t)i * 64 * ldb + 64, AB[1][1] + i * 4096 + wb);

  for (int it = 0; it < NT; ++it) {
    int cur = it & 1;
    asm volatile("s_waitcnt vmcnt(8)" ::: "memory");
    __builtin_amdgcn_sched_barrier(0);
    __builtin_amdgcn_s_barrier();

    const ushort* As = AB[cur][0];
    const ushort* Bs = AB[cur][1];
    #pragma unroll
    for (int kk = 0; kk < 2; ++kk) {
      short8 af[8], bfr[4];
      #pragma unroll
      for (int mi = 0; mi < 8; ++mi) {
        int rr = (wm << 7) + (mi << 4) + l15;
        af[mi] = __builtin_bit_cast(short8,
            ((const uint4*)As)[rr * 8 + ((kk * 4 + l4) ^ (rr & 7))]);
      }
      #pragma unroll
      for (int ni = 0; ni < 4; ++ni) {
        int rr = (wn << 6) + (ni << 4) + l15;
        bfr[ni] = __builtin_bit_cast(short8,
            ((const uint4*)Bs)[rr * 8 + ((kk * 4 + l4) ^ (rr & 7))]);
      }
      #pragma unroll
      for (int mi = 0; mi < 8; ++mi)
        #pragma unroll
        for (int ni = 0; ni < 4; ++ni)
          acc[mi][ni] = __builtin_amdgcn_mfma_f32_16x16x32_bf16(
              af[mi], bfr[ni], acc[mi][ni], 0, 0, 0);
    }

    asm volatile("" ::: "memory");
    __builtin_amdgcn_s_barrier();
    __builtin_amdgcn_sched_barrier(0);
    if (it + 2 < NT) {
      int k0 = (it + 2) * 64;
      ushort* An = AB[cur][0];
      ushort* Bn = AB[cur][1];
      #pragma unroll
      for (int i = 0; i < 4; ++i)
        gload16(pa + (size_t)i * 64 * lda + k0, An + i * 4096 + wb);
      #pragma unroll
      for (int i = 0; i < 4; ++i)
        gload16(pb + (size_t)i * 64 * ldb + k0, Bn + i * 4096 + wb);
    }
  }

  #pragma unroll
  for (int mi = 0; mi < 8; ++mi) {
    int rbase = m0 + (wm << 7) + (mi << 4) + (l4 << 2);
    #pragma unroll
    for (int ni = 0; ni < 4; ++ni) {
      int col = n0 + (wn << 6) + (ni << 4) + l15;
      f32x4 v = acc[mi][ni];
      #pragma unroll
      for (int rr = 0; rr < 4; ++rr) {
        size_t idx = ((size_t)bz * 1024 + rbase + rr) * 1024 + col;
        if (ADDX) C[idx] = v[rr] + X[idx];
        else      C[idx] = v[rr];
      }
    }
  }
}

// ---------------- Kernel 3: gemm2 with FUSED softmax on A --------------------
// out = softmax_rows(S) . Vt^T + X.  A-panel = 256 COMPLETE S rows, so
// softmax is block-local: (1) pre-pass: wave w row-reduces rows w*32..+32
// (coalesced 4KB/row, butterfly shfl max + expsum — softmax_rows' exact fp32
// math) into rowmax/rowinv LDS; (2) K-loop: A reg-staged from fp32 S,
// transformed exp(s-m)*inv -> bf16, ds_write_b128 at XOR-swizzled chunk
// (write-XOR == read-XOR). B keeps gload16 + src-swizzle (R17-verified).
// Sync: single barrier/iter, R15 race-pattern (issue-next -> compute ->
// vmcnt(0) -> transform+write -> syncthreads). Deletes the softmax kernel
// and its 96MB of HBM traffic.
__global__ __launch_bounds__(512, 2) void gemm256_sm(
    const float* __restrict__ S,
    const ushort* __restrict__ B, int ldb,
    float* __restrict__ C, const float* __restrict__ X)
{
  __shared__ ushort Abuf[2][16384];    // [buf][256*64] bf16 P-tile
  __shared__ ushort Bbuf[2][16384];
  __shared__ float rowmax[256], rowinv[256];
  int t = threadIdx.x;

  int g = blockIdx.x;
  int lin = (g & 7) * 32 + (g >> 3);
  int bz = lin >> 4;
  int by = (lin >> 2) & 3;
  int bx = lin & 3;
  int m0 = by << 8, n0 = bx << 8;

  const float*  Sb = S + (size_t)bz * 1024 * 1024 + (size_t)m0 * 1024;
  const ushort* Bb = B + (size_t)bz * 1024 * ldb;
  int w = t >> 6, lane = t & 63;
  int wm = w >> 2, wn = w & 3;
  int l15 = lane & 15, l4 = lane >> 4;

  // ---- pre-pass: row max + 1/sum for rows m0..m0+256 ----
  for (int rr = 0; rr < 32; ++rr) {
    int r = w * 32 + rr;
    const float4* rp = (const float4*)(Sb + (size_t)r * 1024) + lane * 4;
    float4 v0 = rp[0], v1 = rp[1], v2 = rp[2], v3 = rp[3];
    float m = fmaxf(fmaxf(fmaxf(v0.x, v0.y), fmaxf(v0.z, v0.w)),
                    fmaxf(fmaxf(v1.x, v1.y), fmaxf(v1.z, v1.w)));
    m = fmaxf(m, fmaxf(fmaxf(fmaxf(v2.x, v2.y), fmaxf(v2.z, v2.w)),
                       fmaxf(fmaxf(v3.x, v3.y), fmaxf(v3.z, v3.w))));
    #pragma unroll
    for (int off = 32; off > 0; off >>= 1) m = fmaxf(m, __shfl_xor(m, off));
    float s = __expf(v0.x - m) + __expf(v0.y - m) + __expf(v0.z - m) + __expf(v0.w - m)
            + __expf(v1.x - m) + __expf(v1.y - m) + __expf(v1.z - m) + __expf(v1.w - m)
            + __expf(v2.x - m) + __expf(v2.y - m) + __expf(v2.z - m) + __expf(v2.w - m)
            + __expf(v3.x - m) + __expf(v3.y - m) + __expf(v3.z - m) + __expf(v3.w - m);
    #pragma unroll
    for (int off = 32; off > 0; off >>= 1) s += __shfl_xor(s, off);
    if (lane == 0) { rowmax[r] = m; rowinv[r] = 1.0f / s; }
  }
  __syncthreads();

  // staging maps
  int swc = (t & 7) ^ ((t >> 3) & 7);
  const ushort* pb = Bb + (size_t)(n0 + (t >> 3)) * ldb + swc * 8;
  int wb = w * 512;
  int ci = t & 7, rb = t >> 3;       // A: chunk ci, rows rb + 64*gi

  f32x4 acc[8][4] = {};
  constexpr int NT = 16;
  float4 sreg[4][2];

  // A-stage helper (macro-free, inlined twice)
  // load tile k0 into sreg
  #define LOAD_A(k0_)                                                        \
    _Pragma("unroll")                                                        \
    for (int gi = 0; gi < 4; ++gi) {                                         \
      const float* src = Sb + (size_t)(rb + 64 * gi) * 1024 + (k0_) + ci * 8;\
      sreg[gi][0] = *(const float4*)src;                                     \
      sreg[gi][1] = *(const float4*)(src + 4);                               \
    }
  #define WRITE_A(dst_)                                                      \
    _Pragma("unroll")                                                        \
    for (int gi = 0; gi < 4; ++gi) {                                         \
      int r = rb + 64 * gi;                                                  \
      float mx = rowmax[r], iv = rowinv[r];                                  \
      union { ushort s[8]; uint4 q; } pk;                                    \
      _Pragma("unroll")                                                      \
      for (int j = 0; j < 4; ++j) {                                          \
        pk.s[j]     = f2bf(__expf(((const float*)&sreg[gi][0])[j] - mx) * iv);\
        pk.s[4 + j] = f2bf(__expf(((const float*)&sreg[gi][1])[j] - mx) * iv);\
      }                                                                      \
      ((uint4*)(dst_))[r * 8 + (ci ^ (r & 7))] = pk.q;                       \
    }

  // prologue: tile 0
  LOAD_A(0)
  #pragma unroll
  for (int i = 0; i < 4; ++i)
    gload16(pb + (size_t)i * 64 * ldb, Bbuf[0] + i * 4096 + wb);
  asm volatile("s_waitcnt vmcnt(0)" ::: "memory");
  WRITE_A(Abuf[0])
  __syncthreads();

  for (int it = 0; it < NT; ++it) {
    int cur = it & 1;
    if (it + 1 < NT) {
      LOAD_A((it + 1) * 64)
      #pragma unroll
      for (int i = 0; i < 4; ++i)
        gload16(pb + (size_t)i * 64 * ldb + (it + 1) * 64,
                Bbuf[cur ^ 1] + i * 4096 + wb);
    }
    const ushort* As = Abuf[cur];
    const ushort* Bs = Bbuf[cur];
    #pragma unroll
    for (int kk = 0; kk < 2; ++kk) {
      short8 af[8], bfr[4];
      #pragma unroll
      for (int mi = 0; mi < 8; ++mi) {
        int rr = (wm << 7) + (mi << 4) + l15;
        af[mi] = __builtin_bit_cast(short8,
            ((const uint4*)As)[rr * 8 + ((kk * 4 + l4) ^ (rr & 7))]);
      }
      #pragma unroll
      for (int ni = 0; ni < 4; ++ni) {
        int rr = (wn << 6) + (ni << 4) + l15;
        bfr[ni] = __builtin_bit_cast(short8,
            ((const uint4*)Bs)[rr * 8 + ((kk * 4 + l4) ^ (rr & 7))]);
      }
      #pragma unroll
      for (int mi = 0; mi < 8; ++mi)
        #pragma unroll
        for (int ni = 0; ni < 4; ++ni)
          acc[mi][ni] = __builtin_amdgcn_mfma_f32_16x16x32_bf16(
              af[mi], bfr[ni], acc[mi][ni], 0, 0, 0);
    }
    asm volatile("s_waitcnt vmcnt(0)" ::: "memory");  // sreg + B-LDS landed
    if (it + 1 < NT) {
      WRITE_A(Abuf[cur ^ 1])
    }
    __syncthreads();   // writes visible; all reads of cur done
  }

  #pragma unroll
  for (int mi = 0; mi < 8; ++mi) {
    int rbase = m0 + (wm << 7) + (mi << 4) + (l4 << 2);
    #pragma unroll
    for (int ni = 0; ni < 4; ++ni) {
      int col = n0 + (wn << 6) + (ni << 4) + l15;
      f32x4 v = acc[mi][ni];
      #pragma unroll
      for (int rr = 0; rr < 4; ++rr) {
        size_t idx = ((size_t)bz * 1024 + rbase + rr) * 1024 + col;
        C[idx] = v[rr] + X[idx];
      }
    }
  }
  #undef LOAD_A
  #undef WRITE_A
}

// ---------------- Launch -----------------------------------------------------
extern "C" void kernel_launch(void* const* d_in, const int* in_sizes, int n_in,
                              void* d_out, int out_size, void* d_ws, size_t ws_size,
                              hipStream_t stream) {
  const float* x  = (const float*)d_in[0];
  const float* Wq = (const float*)d_in[1];
  const float* bq = (const float*)d_in[2];
  const float* Wk = (const float*)d_in[3];
  const float* bk = (const float*)d_in[4];
  const float* Wv = (const float*)d_in[5];
  const float* bv = (const float*)d_in[6];
  float* out = (float*)d_out;

  char* wsb = (char*)d_ws;
  ushort* Qt2 = (ushort*)wsb;                          // 12,582,912 B
  ushort* Kt2 = (ushort*)(wsb + 12582912);             // 12,582,912 B
  ushort* Vt  = (ushort*)(wsb + 25165824);             // 33,554,432 B
  float*  S   = (float*)(wsb + 58720256);              // 67,108,864 B
  ushort* Wpk = (ushort*)(wsb + 92274688);             // inside S, dead before gemm1
  float*  bpk = (float*)(wsb + 92274688 + 24576);

  prep_w2<<<49, 256, 0, stream>>>(Wq, bq, Wk, bk, Wv, bv, Wpk, bpk);
  proj10<<<2048, 256, 0, stream>>>(x, Wpk, bpk, Qt2, Kt2, Vt);
  gemm256<384, false><<<256, 512, 0, stream>>>(Qt2, 384, Kt2, 384, S, nullptr);
  gemm256_sm<<<256, 512, 0, stream>>>(S, Vt, 1024, out, x);
}

// Round 20
// 123.954 us; speedup vs baseline: 1.2245x; 1.2245x over previous
//
#include <hip/hip_runtime.h>
#include <stdint.h>

typedef uint32_t u32;
typedef __attribute__((ext_vector_type(4))) float f32x4;
typedef __attribute__((ext_vector_type(8))) short short8;

#define NBATCH 16
#define NPIX   16384      // H*W
#define NPB    1048576    // per-batch flat elems (C*H*W = 1024*1024)

__device__ __forceinline__ ushort f2bf(float f) {
  u32 b = __builtin_bit_cast(u32, f);
  return (ushort)((b + 0x7FFFu + ((b >> 16) & 1u)) >> 16);
}
__device__ __forceinline__ float bf2f(ushort h) {
  return __builtin_bit_cast(float, (u32)h << 16);
}

// async global->LDS, 16B per lane. LDS dest must be wave-uniform base;
// HW scatters lane i at base + i*16. Global source is per-lane.
__device__ __forceinline__ void gload16(const void* g, void* l) {
  __builtin_amdgcn_global_load_lds(
      (const __attribute__((address_space(1))) u32*)g,
      (__attribute__((address_space(3))) u32*)l,
      16, 0, 0);
}

// ---------------- Kernel 0: pack weights for MFMA-proj -----------------------
// Wpk[96][128] bf16: rows 0..15 = q,k: cols[0:64]=Wh (round), [64:128]=Wl
// (W - Wh, exact split). Rows 16..79 = v: cols[0:64]=bf16(Wv), rest 0.
__global__ void prep_w2(const float* __restrict__ Wq, const float* __restrict__ bq,
                        const float* __restrict__ Wk, const float* __restrict__ bk,
                        const float* __restrict__ Wv, const float* __restrict__ bv,
                        ushort* __restrict__ Wpk, float* __restrict__ bpk)
{
  int gid = blockIdx.x * 256 + threadIdx.x;
  if (gid < 12288) {
    int m = gid >> 7, kk = gid & 127;
    int ch = kk & 63;
    ushort outv = 0;
    if (m < 8) {
      float wv = Wq[m * 64 + ch];
      ushort h = f2bf(wv);
      outv = (kk < 64) ? h : f2bf(wv - bf2f(h));
    } else if (m < 16) {
      float wv = Wk[(m - 8) * 64 + ch];
      ushort h = f2bf(wv);
      outv = (kk < 64) ? h : f2bf(wv - bf2f(h));
    } else if (m < 80) {
      outv = (kk < 64) ? f2bf(Wv[(m - 16) * 64 + ch]) : (ushort)0;
    }
    Wpk[gid] = outv;
  } else if (gid < 12368) {
    int o = gid - 12288;
    bpk[o] = (o < 8) ? bq[o] : (o < 16 ? bk[o - 8] : bv[o - 16]);
  }
}

// ---------------- Kernel 1: MFMA proj, 2-chunk self-pipelined ----------------
// Block = (batch b, 16-l pair) = two 8-l chunks. Both chunks' staging issued
// up-front (16 gloads/wave in flight); counted vmcnt(8) + raw barrier (c0
// landed, c1 flies under c0's compute+epilogue). Compute/epilogue = R15-
// verified proj10 body. Qt2/Kt2 slimmed to 2 regions (stride 256):
// Q=[qh][ql], K=[kh][kl]; gemm1 does the 3-term product via offset tables.
__global__ __launch_bounds__(256) void proj12(
    const float* __restrict__ x, const ushort* __restrict__ Wpk,
    const float* __restrict__ bpk,
    ushort* __restrict__ Qt2, ushort* __restrict__ Kt2,
    ushort* __restrict__ Vt)
{
  __shared__ __align__(16) char smem[65536];
  int t = threadIdx.x;
  int w = t >> 6, lane = t & 63;
  int l15 = lane & 15, l4 = lane >> 4;

  // XCD-chunk remap: 1024 blocks, 128 per XCD = 2 batches, consecutive l0.
  int g = blockIdx.x;
  int lin = (g & 7) * 128 + (g >> 3);
  int b = lin >> 6;
  int l0 = (lin & 63) << 4;     // 16 l per block; chunks at l0, l0+8

  // A-frags first (so the staging vmcnt count below is exact):
  // frag(mt,kc)[lane] = Wpk[mt*16 + l15][kc*32 + l4*8 ..+8]
  const uint4* Wp4 = (const uint4*)Wpk;   // row stride 16 uint4
  uint4 Afrag[12];
  #pragma unroll
  for (int kc = 0; kc < 4; ++kc)
    Afrag[kc] = Wp4[l15 * 16 + kc * 4 + l4];
  #pragma unroll
  for (int mt = 1; mt < 5; ++mt)
    #pragma unroll
    for (int kc = 0; kc < 2; ++kc)
      Afrag[2 + mt * 2 + kc] = Wp4[(mt * 16 + l15) * 16 + kc * 4 + l4];
  __builtin_amdgcn_sched_barrier(0);

  // stage both chunks: slot f (16B) = x[ch][tc*1024 + lc + half*4 ..+4),
  // f = ch*32 + tc*2 + half  ->  xs[ch][tc*8 + half*4 ..]  (R15-verified map)
  #pragma unroll
  for (int c = 0; c < 2; ++c) {
    const float* xb = x + (size_t)b * NPB + l0 + c * 8;
    float* xs = (float*)(smem + c * 32768);
    #pragma unroll
    for (int it = 0; it < 8; ++it) {
      int f0 = (it * 4 + w) * 64;
      int f = f0 + lane;
      int ch = f >> 5, r2 = f & 31, tc = r2 >> 1, half = r2 & 1;
      gload16(xb + (size_t)ch * NPIX + tc * 1024 + half * 4, xs + f0 * 4);
    }
  }
  // c0's 8 + the 12 Afrag loads landed; c1's 8 stay in flight.
  asm volatile("s_waitcnt vmcnt(8)" ::: "memory");
  __builtin_amdgcn_sched_barrier(0);
  __builtin_amdgcn_s_barrier();

  // per-chunk compute + epilogue (R15-verified body)
  auto do_chunk = [&](char* region, int lc) {
    float* xs = (float*)region;
    f32x4 acc[5][2];
    #pragma unroll
    for (int mt = 0; mt < 5; ++mt) {
      f32x4 bv4;
      #pragma unroll
      for (int r = 0; r < 4; ++r) bv4[r] = bpk[mt * 16 + l4 * 4 + r];
      acc[mt][0] = bv4; acc[mt][1] = bv4;
    }
    #pragma unroll
    for (int i = 0; i < 2; ++i) {
      int px = (w * 2 + i) * 16 + l15;
      u32 xr[16];
      #pragma unroll
      for (int kc = 0; kc < 2; ++kc)
        #pragma unroll
        for (int j = 0; j < 8; ++j)
          xr[kc * 8 + j] = ((const u32*)xs)[(kc * 32 + l4 * 8 + j) * 128 + px];
      uint4 bxh[2], bxl[2];
      #pragma unroll
      for (int kc = 0; kc < 2; ++kc)
        #pragma unroll
        for (int p = 0; p < 4; ++p) {
          u32 a = xr[kc * 8 + 2 * p], cc = xr[kc * 8 + 2 * p + 1];
          ((u32*)&bxh[kc])[p] = (a >> 16) | (cc & 0xFFFF0000u);
          float fa = __builtin_bit_cast(float, a) -
                     __builtin_bit_cast(float, a & 0xFFFF0000u);
          float fc = __builtin_bit_cast(float, cc) -
                     __builtin_bit_cast(float, cc & 0xFFFF0000u);
          u32 la = __builtin_bit_cast(u32, fa), lc2 = __builtin_bit_cast(u32, fc);
          ((u32*)&bxl[kc])[p] = (la >> 16) | (lc2 & 0xFFFF0000u);
        }
      short8 h0 = __builtin_bit_cast(short8, bxh[0]);
      short8 h1 = __builtin_bit_cast(short8, bxh[1]);
      short8 s0 = __builtin_bit_cast(short8, bxl[0]);
      short8 s1 = __builtin_bit_cast(short8, bxl[1]);
      acc[0][i] = __builtin_amdgcn_mfma_f32_16x16x32_bf16(
          __builtin_bit_cast(short8, Afrag[0]), h0, acc[0][i], 0, 0, 0);
      acc[0][i] = __builtin_amdgcn_mfma_f32_16x16x32_bf16(
          __builtin_bit_cast(short8, Afrag[1]), h1, acc[0][i], 0, 0, 0);
      acc[0][i] = __builtin_amdgcn_mfma_f32_16x16x32_bf16(
          __builtin_bit_cast(short8, Afrag[0]), s0, acc[0][i], 0, 0, 0);
      acc[0][i] = __builtin_amdgcn_mfma_f32_16x16x32_bf16(
          __builtin_bit_cast(short8, Afrag[1]), s1, acc[0][i], 0, 0, 0);
      acc[0][i] = __builtin_amdgcn_mfma_f32_16x16x32_bf16(
          __builtin_bit_cast(short8, Afrag[2]), h0, acc[0][i], 0, 0, 0);
      acc[0][i] = __builtin_amdgcn_mfma_f32_16x16x32_bf16(
          __builtin_bit_cast(short8, Afrag[3]), h1, acc[0][i], 0, 0, 0);
      #pragma unroll
      for (int mt = 1; mt < 5; ++mt) {
        acc[mt][i] = __builtin_amdgcn_mfma_f32_16x16x32_bf16(
            __builtin_bit_cast(short8, Afrag[2 + mt * 2]), h0, acc[mt][i], 0, 0, 0);
        acc[mt][i] = __builtin_amdgcn_mfma_f32_16x16x32_bf16(
            __builtin_bit_cast(short8, Afrag[3 + mt * 2]), h1, acc[mt][i], 0, 0, 0);
      }
    }
    __syncthreads();   // all xs reads done before epilogue overwrites region

    float*  qkl = (float*)region;                    // [16][132]
    ushort* vl  = (ushort*)(region + 16 * 132 * 4);  // [64][136]
    #pragma unroll
    for (int i = 0; i < 2; ++i) {
      int px = (w * 2 + i) * 16 + l15;
      #pragma unroll
      for (int r = 0; r < 4; ++r)
        qkl[(l4 * 4 + r) * 132 + px] = acc[0][i][r];
      #pragma unroll
      for (int mt = 1; mt < 5; ++mt)
        #pragma unroll
        for (int r = 0; r < 4; ++r)
          vl[((mt - 1) * 16 + l4 * 4 + r) * 136 + px] = f2bf(acc[mt][i][r]);
    }
    __syncthreads();

    if (t < 128) {
      int l = t >> 4, tcc = t & 15;
      size_t lrow = (size_t)b * 1024 + lc + l;
      int px = tcc * 8 + l;

      // Q/K split bf16, slim layout: Q=[qh][ql], K=[kh][kl] (stride 256);
      // gemm1's offset tables realize qh*kh + ql*kh + qh*kl.
      union { ushort s[8]; uint4 v; } qh, ql, kh, kl;
      #pragma unroll
      for (int o = 0; o < 8; ++o) {
        float qv = qkl[o * 132 + px];
        ushort h = f2bf(qv);
        qh.s[o] = h; ql.s[o] = f2bf(qv - bf2f(h));
        float kv = qkl[(8 + o) * 132 + px];
        h = f2bf(kv);
        kh.s[o] = h; kl.s[o] = f2bf(kv - bf2f(h));
      }
      ushort* qrow = Qt2 + lrow * 256 + tcc * 8;
      *(uint4*)qrow         = qh.v;
      *(uint4*)(qrow + 128) = ql.v;
      ushort* krow = Kt2 + lrow * 256 + tcc * 8;
      *(uint4*)krow         = kh.v;
      *(uint4*)(krow + 128) = kl.v;

      ushort* vrow = Vt + lrow * 1024;
      #pragma unroll
      for (int it = 0; it < 4; ++it) {
        int c2 = (it << 4) + tcc;
        union { ushort s[16]; uint4 q[2]; } ov;
        #pragma unroll
        for (int tt = 0; tt < 16; ++tt)
          ov.s[tt] = vl[c2 * 136 + tt * 8 + l];
        *(uint4*)(vrow + c2 * 16)     = ov.q[0];
        *(uint4*)(vrow + c2 * 16 + 8) = ov.q[1];
      }
    }
  };

  do_chunk(smem, l0);            // c1's loads land under this
  do_chunk(smem + 32768, l0 + 8);  // drained by c0's internal barriers
}

// ---------------- Kernel 2: gemm1 = S scores, 3-term split via tables --------
// S[i][j] = qh_i.kh_j + ql_i.kh_j + qh_i.kl_j over 6 (KA,KB) tiles.
// Structure = R17-verified gemm256 (counted vmcnt(8), 2 raw barriers/iter).
__global__ __launch_bounds__(512, 2) void gemm_qk(
    const ushort* __restrict__ A,
    const ushort* __restrict__ B,
    float* __restrict__ C)
{
  __shared__ ushort AB[2][2][16384];   // [buf][A/B][256*64]
  int t = threadIdx.x;

  int g = blockIdx.x;
  int lin = (g & 7) * 32 + (g >> 3);
  int bz = lin >> 4;
  int by = (lin >> 2) & 3;
  int bx = lin & 3;
  int m0 = by << 8, n0 = bx << 8;

  const ushort* Ab = A + (size_t)bz * 1024 * 256;
  const ushort* Bb = B + (size_t)bz * 1024 * 256;
  int w = t >> 6, lane = t & 63;
  int wm = w >> 2, wn = w & 3;
  int l15 = lane & 15, l4 = lane >> 4;

  int swc = (t & 7) ^ ((t >> 3) & 7);
  const ushort* pa = Ab + (size_t)(m0 + (t >> 3)) * 256 + swc * 8;
  const ushort* pb = Bb + (size_t)(n0 + (t >> 3)) * 256 + swc * 8;
  int wb = w * 512;

  constexpr int KA[6] = {0, 64, 128, 192, 0, 64};
  constexpr int KB[6] = {0, 64, 0, 64, 128, 192};

  f32x4 acc[8][4] = {};

  #pragma unroll
  for (int i = 0; i < 4; ++i)
    gload16(pa + (size_t)i * 64 * 256 + KA[0], AB[0][0] + i * 4096 + wb);
  #pragma unroll
  for (int i = 0; i < 4; ++i)
    gload16(pb + (size_t)i * 64 * 256 + KB[0], AB[0][1] + i * 4096 + wb);
  #pragma unroll
  for (int i = 0; i < 4; ++i)
    gload16(pa + (size_t)i * 64 * 256 + KA[1], AB[1][0] + i * 4096 + wb);
  #pragma unroll
  for (int i = 0; i < 4; ++i)
    gload16(pb + (size_t)i * 64 * 256 + KB[1], AB[1][1] + i * 4096 + wb);

  for (int it = 0; it < 6; ++it) {
    int cur = it & 1;
    asm volatile("s_waitcnt vmcnt(8)" ::: "memory");
    __builtin_amdgcn_sched_barrier(0);
    __builtin_amdgcn_s_barrier();

    const ushort* As = AB[cur][0];
    const ushort* Bs = AB[cur][1];
    #pragma unroll
    for (int kk = 0; kk < 2; ++kk) {
      short8 af[8], bfr[4];
      #pragma unroll
      for (int mi = 0; mi < 8; ++mi) {
        int rr = (wm << 7) + (mi << 4) + l15;
        af[mi] = __builtin_bit_cast(short8,
            ((const uint4*)As)[rr * 8 + ((kk * 4 + l4) ^ (rr & 7))]);
      }
      #pragma unroll
      for (int ni = 0; ni < 4; ++ni) {
        int rr = (wn << 6) + (ni << 4) + l15;
        bfr[ni] = __builtin_bit_cast(short8,
            ((const uint4*)Bs)[rr * 8 + ((kk * 4 + l4) ^ (rr & 7))]);
      }
      #pragma unroll
      for (int mi = 0; mi < 8; ++mi)
        #pragma unroll
        for (int ni = 0; ni < 4; ++ni)
          acc[mi][ni] = __builtin_amdgcn_mfma_f32_16x16x32_bf16(
              af[mi], bfr[ni], acc[mi][ni], 0, 0, 0);
    }

    asm volatile("" ::: "memory");
    __builtin_amdgcn_s_barrier();
    __builtin_amdgcn_sched_barrier(0);
    if (it + 2 < 6) {
      ushort* An = AB[cur][0];
      ushort* Bn = AB[cur][1];
      #pragma unroll
      for (int i = 0; i < 4; ++i)
        gload16(pa + (size_t)i * 64 * 256 + KA[it + 2], An + i * 4096 + wb);
      #pragma unroll
      for (int i = 0; i < 4; ++i)
        gload16(pb + (size_t)i * 64 * 256 + KB[it + 2], Bn + i * 4096 + wb);
    }
  }

  #pragma unroll
  for (int mi = 0; mi < 8; ++mi) {
    int rbase = m0 + (wm << 7) + (mi << 4) + (l4 << 2);
    #pragma unroll
    for (int ni = 0; ni < 4; ++ni) {
      int col = n0 + (wn << 6) + (ni << 4) + l15;
      f32x4 v = acc[mi][ni];
      #pragma unroll
      for (int rr = 0; rr < 4; ++rr) {
        size_t idx = ((size_t)bz * 1024 + rbase + rr) * 1024 + col;
        C[idx] = v[rr];
      }
    }
  }
}

// ---------------- Kernel 4: 256x256 NT bf16 GEMM (R17-verified, gemm2) ------
template<int KTOT, bool ADDX>
__global__ __launch_bounds__(512, 2) void gemm256(
    const ushort* __restrict__ A, int lda,
    const ushort* __restrict__ B, int ldb,
    float* __restrict__ C, const float* __restrict__ X)
{
  __shared__ ushort AB[2][2][16384];   // [buf][A/B][256*64]
  int t = threadIdx.x;

  int g = blockIdx.x;
  int lin = (g & 7) * 32 + (g >> 3);
  int bz = lin >> 4;
  int by = (lin >> 2) & 3;
  int bx = lin & 3;
  int m0 = by << 8, n0 = bx << 8;

  const ushort* Ab = A + (size_t)bz * 1024 * lda;
  const ushort* Bb = B + (size_t)bz * 1024 * ldb;
  int w = t >> 6, lane = t & 63;
  int wm = w >> 2, wn = w & 3;
  int l15 = lane & 15, l4 = lane >> 4;

  int swc = (t & 7) ^ ((t >> 3) & 7);
  const ushort* pa = Ab + (size_t)(m0 + (t >> 3)) * lda + swc * 8;
  const ushort* pb = Bb + (size_t)(n0 + (t >> 3)) * ldb + swc * 8;
  int wb = w * 512;

  f32x4 acc[8][4] = {};
  constexpr int NT = KTOT / 64;

  #pragma unroll
  for (int i = 0; i < 4; ++i)
    gload16(pa + (size_t)i * 64 * lda, AB[0][0] + i * 4096 + wb);
  #pragma unroll
  for (int i = 0; i < 4; ++i)
    gload16(pb + (size_t)i * 64 * ldb, AB[0][1] + i * 4096 + wb);
  #pragma unroll
  for (int i = 0; i < 4; ++i)
    gload16(pa + (size_t)i * 64 * lda + 64, AB[1][0] + i * 4096 + wb);
  #pragma unroll
  for (int i = 0; i < 4; ++i)
    gload16(pb + (size_t)i * 64 * ldb + 64, AB[1][1] + i * 4096 + wb);

  for (int it = 0; it < NT; ++it) {
    int cur = it & 1;
    asm volatile("s_waitcnt vmcnt(8)" ::: "memory");
    __builtin_amdgcn_sched_barrier(0);
    __builtin_amdgcn_s_barrier();

    const ushort* As = AB[cur][0];
    const ushort* Bs = AB[cur][1];
    #pragma unroll
    for (int kk = 0; kk < 2; ++kk) {
      short8 af[8], bfr[4];
      #pragma unroll
      for (int mi = 0; mi < 8; ++mi) {
        int rr = (wm << 7) + (mi << 4) + l15;
        af[mi] = __builtin_bit_cast(short8,
            ((const uint4*)As)[rr * 8 + ((kk * 4 + l4) ^ (rr & 7))]);
      }
      #pragma unroll
      for (int ni = 0; ni < 4; ++ni) {
        int rr = (wn << 6) + (ni << 4) + l15;
        bfr[ni] = __builtin_bit_cast(short8,
            ((const uint4*)Bs)[rr * 8 + ((kk * 4 + l4) ^ (rr & 7))]);
      }
      #pragma unroll
      for (int mi = 0; mi < 8; ++mi)
        #pragma unroll
        for (int ni = 0; ni < 4; ++ni)
          acc[mi][ni] = __builtin_amdgcn_mfma_f32_16x16x32_bf16(
              af[mi], bfr[ni], acc[mi][ni], 0, 0, 0);
    }

    asm volatile("" ::: "memory");
    __builtin_amdgcn_s_barrier();
    __builtin_amdgcn_sched_barrier(0);
    if (it + 2 < NT) {
      int k0 = (it + 2) * 64;
      ushort* An = AB[cur][0];
      ushort* Bn = AB[cur][1];
      #pragma unroll
      for (int i = 0; i < 4; ++i)
        gload16(pa + (size_t)i * 64 * lda + k0, An + i * 4096 + wb);
      #pragma unroll
      for (int i = 0; i < 4; ++i)
        gload16(pb + (size_t)i * 64 * ldb + k0, Bn + i * 4096 + wb);
    }
  }

  #pragma unroll
  for (int mi = 0; mi < 8; ++mi) {
    int rbase = m0 + (wm << 7) + (mi << 4) + (l4 << 2);
    #pragma unroll
    for (int ni = 0; ni < 4; ++ni) {
      int col = n0 + (wn << 6) + (ni << 4) + l15;
      f32x4 v = acc[mi][ni];
      #pragma unroll
      for (int rr = 0; rr < 4; ++rr) {
        size_t idx = ((size_t)bz * 1024 + rbase + rr) * 1024 + col;
        if (ADDX) C[idx] = v[rr] + X[idx];
        else      C[idx] = v[rr];
      }
    }
  }
}

// ---------------- Kernel 3: row softmax, P bf16 in place ---------------------
__global__ __launch_bounds__(256) void softmax_rows(float* __restrict__ S)
{
  size_t rowi = blockIdx.x;
  float* srow = S + rowi * 1024;
  int t = threadIdx.x;
  float4 v = ((const float4*)srow)[t];
  float m = fmaxf(fmaxf(v.x, v.y), fmaxf(v.z, v.w));
  #pragma unroll
  for (int off = 32; off > 0; off >>= 1) m = fmaxf(m, __shfl_xor(m, off));
  __shared__ float red[8];
  int wid = t >> 6, lane = t & 63;
  if (lane == 0) red[wid] = m;
  __syncthreads();
  m = fmaxf(fmaxf(red[0], red[1]), fmaxf(red[2], red[3]));
  float e0 = __expf(v.x - m), e1 = __expf(v.y - m);
  float e2 = __expf(v.z - m), e3 = __expf(v.w - m);
  float s = e0 + e1 + e2 + e3;
  #pragma unroll
  for (int off = 32; off > 0; off >>= 1) s += __shfl_xor(s, off);
  if (lane == 0) red[4 + wid] = s;
  __syncthreads();
  s = red[4] + red[5] + red[6] + red[7];
  float inv = 1.0f / s;
  union { ushort h[4]; uint2 q; } pk;
  pk.h[0] = f2bf(e0 * inv); pk.h[1] = f2bf(e1 * inv);
  pk.h[2] = f2bf(e2 * inv); pk.h[3] = f2bf(e3 * inv);
  ((uint2*)srow)[t] = pk.q;
}

// ---------------- Launch -----------------------------------------------------
extern "C" void kernel_launch(void* const* d_in, const int* in_sizes, int n_in,
                              void* d_out, int out_size, void* d_ws, size_t ws_size,
                              hipStream_t stream) {
  const float* x  = (const float*)d_in[0];
  const float* Wq = (const float*)d_in[1];
  const float* bq = (const float*)d_in[2];
  const float* Wk = (const float*)d_in[3];
  const float* bk = (const float*)d_in[4];
  const float* Wv = (const float*)d_in[5];
  const float* bv = (const float*)d_in[6];
  float* out = (float*)d_out;

  char* wsb = (char*)d_ws;
  ushort* Qt2 = (ushort*)wsb;                          //  8,388,608 B
  ushort* Kt2 = (ushort*)(wsb + 8388608);              //  8,388,608 B
  ushort* Vt  = (ushort*)(wsb + 16777216);             // 33,554,432 B
  float*  S   = (float*)(wsb + 50331648);              // 67,108,864 B
  ushort* Wpk = (ushort*)(wsb + 117440512);            // past S (persistent)
  float*  bpk = (float*)(wsb + 117440512 + 24576);

  prep_w2<<<49, 256, 0, stream>>>(Wq, bq, Wk, bk, Wv, bv, Wpk, bpk);
  proj12<<<1024, 256, 0, stream>>>(x, Wpk, bpk, Qt2, Kt2, Vt);
  gemm_qk<<<256, 512, 0, stream>>>(Qt2, Kt2, S);
  softmax_rows<<<16384, 256, 0, stream>>>(S);
  gemm256<1024, true><<<256, 512, 0, stream>>>((const ushort*)S, 2048, Vt, 1024, out, x);
}